// Round 12
// baseline (6096.275 us; speedup 1.0000x reference)
//
#include <hip/hip_runtime.h>
#include <hip/hip_fp16.h>

#define B_   32
#define S_   256
#define EMB_ 512
#define H_   1024
#define G4_  4096
#define NL_  5
#define NBLK 64

typedef _Float16 f16x8 __attribute__((ext_vector_type(8)));
typedef float f32x4 __attribute__((ext_vector_type(4)));
typedef unsigned long long ull;

__device__ inline ull ldq(const ull* p) {
  return __hip_atomic_load(p, __ATOMIC_RELAXED, __HIP_MEMORY_SCOPE_AGENT);
}
__device__ inline void stw(unsigned* p, unsigned v) {
  __hip_atomic_store(p, v, __ATOMIC_RELAXED, __HIP_MEMORY_SCOPE_AGENT);
}

// ---------------------------------------------------------------------------
// K0: transpose src [K][4096] -> dst [4096][K]. grid (128, K/32).
__global__ __launch_bounds__(256) void k_transposeK(const float* __restrict__ src,
                                                    float* __restrict__ dst, int K) {
  __shared__ float tile[32][33];
  int c0 = blockIdx.x * 32, k0 = blockIdx.y * 32;
  int tx = threadIdx.x & 31, ty = threadIdx.x >> 5;
#pragma unroll
  for (int i = 0; i < 4; ++i)
    tile[ty + 8 * i][tx] = src[(size_t)(k0 + ty + 8 * i) * G4_ + c0 + tx];
  __syncthreads();
#pragma unroll
  for (int i = 0; i < 4; ++i)
    dst[(size_t)(c0 + ty + 8 * i) * K + k0 + tx] = tile[tx][ty + 8 * i];
}

// ---------------------------------------------------------------------------
// K0b: U -> fp16 MFMA B-fragments, hi plane (Uhi) + lo*1024 plane (Ulo).
// Uhi flat == gid: (((bx*4+cg)*4+ks)*8+s8)*64 + l  (bx 0..63, 16 units/blk)
// Ulo flat: (((bx*8 + w)*4 + s)*4 + cg)*64 + l, w = ks*2+(s8>>2), s = s8&3
// value U[k][gcol]: k = ks*256+s8*32+(l>>4)*8+j, n16=l&15,
// gcol = (n16&3)*1024 + (bx*4+cg)*4 + (n16>>2).
__global__ __launch_bounds__(256) void k_prepU162(const float* __restrict__ Ut,
                                                  f16x8* __restrict__ Uhi,
                                                  f16x8* __restrict__ Ulo) {
  int gid = blockIdx.x * 256 + threadIdx.x;   // 524288 total
  int l = gid & 63;
  int rest = gid >> 6;
  int s8 = rest & 7, ks = (rest >> 3) & 3, cg = (rest >> 5) & 3, bx = rest >> 7;
  int ug = bx * 4 + cg;
  int n16 = l & 15;
  int kgrp = l >> 4;
  int gcol = (n16 & 3) * 1024 + ug * 4 + (n16 >> 2);
  int k = ks * 256 + s8 * 32 + kgrp * 8;
  const float4* f = (const float4*)(Ut + (size_t)gcol * H_ + k);
  float4 f0 = f[0], f1 = f[1];
  float v[8] = {f0.x, f0.y, f0.z, f0.w, f1.x, f1.y, f1.z, f1.w};
  f16x8 vh, vl;
#pragma unroll
  for (int j = 0; j < 8; ++j) {
    _Float16 hi = (_Float16)v[j];
    vh[j] = hi;
    vl[j] = (_Float16)((v[j] - (float)hi) * 1024.f);
  }
  Uhi[gid] = vh;
  int w = ks * 2 + (s8 >> 2), s = s8 & 3;
  Ulo[(size_t)(((bx * 8 + w) * 4 + s) * 4 + cg) * 64 + l] = vl;
}

// ---------------------------------------------------------------------------
// K0c: W -> fp16 MFMA B-fragments (single plane). (unchanged, proven)
__global__ __launch_bounds__(256) void k_prepW16(const float* __restrict__ Wt,
                                                 unsigned short* __restrict__ Wf16) {
  int gid = blockIdx.x * 256 + threadIdx.x;   // 262144 total
  int l = gid & 63, fi = gid >> 6;
  int kc = fi & 15, ug = fi >> 4;
  int n16 = l & 15, kgrp = l >> 4;
  int gcol = (n16 & 3) * 1024 + ug * 4 + (n16 >> 2);
  const float4* f = (const float4*)(Wt + (size_t)gcol * 512 + kc * 32 + kgrp * 8);
  float4 f0 = f[0], f1 = f[1];
  float v[8] = {f0.x, f0.y, f0.z, f0.w, f1.x, f1.y, f1.z, f1.w};
  union { unsigned short u[8]; uint4 q; } o;
#pragma unroll
  for (int j = 0; j < 8; ++j) o.u[j] = __half_as_ushort(__float2half_rn(v[j]));
  *(uint4*)(Wf16 + ((size_t)fi * 64 + l) * 8) = o.q;
}

// ---------------------------------------------------------------------------
// K0d: gather emb rows -> Xf16 [256 s][32 b][512 e] fp16. (unchanged, proven)
__global__ __launch_bounds__(256) void k_prepX(const int* __restrict__ tokens,
                                               const float* __restrict__ emb,
                                               unsigned short* __restrict__ Xf16) {
  int gid = blockIdx.x * 256 + threadIdx.x;   // 524288 total
  int seg = gid & 63, row = gid >> 6;
  int s = row >> 5, b = row & 31;
  int tok = tokens[b * 256 + s];
  const float4* f = (const float4*)(emb + (size_t)tok * EMB_ + seg * 8);
  float4 f0 = f[0], f1 = f[1];
  float v[8] = {f0.x, f0.y, f0.z, f0.w, f1.x, f1.y, f1.z, f1.w};
  union { unsigned short u[8]; uint4 q; } o;
#pragma unroll
  for (int j = 0; j < 8; ++j) o.u[j] = __half_as_ushort(__float2half_rn(v[j]));
  *(uint4*)(Xf16 + (size_t)row * 512 + seg * 8) = o.q;
}

// ---------------------------------------------------------------------------
// K2: persistent steps v8 (r11 design, reduction-read FIXED).
// grid 64 x 512 (8 waves). Block bx owns 16 units (64 gate cols, cg 0..3);
// wave w = K-slice [w*128,(w+1)*128). U-hi fp16 in LDS (staged once);
// U-lo*1024 reloaded from L2 each step (address-stable). h: fp16 pair-packed
// words in A-fragment layout at LLC; sync: r9-proven per-producer flags.
// Reduction: LDS atomicAdd, IDENTITY layout (writer's rot only staggers
// iteration order; reader must use identity offsets). 2 barriers/step.
// h word idx: ((m*128 + kidx)*16 + row)*4 + (j>>1); b=m*16+row, k=kidx*8+j.
__global__ __launch_bounds__(512, 2) void k_steps8(
    const f16x8* __restrict__ Uhi,
    const f16x8* __restrict__ Ulo,
    const unsigned short* __restrict__ Wf16,
    const unsigned short* __restrict__ Xf16,
    const float* __restrict__ bias,
    unsigned* __restrict__ T0, unsigned* __restrict__ T1,
    unsigned* __restrict__ flg) {
  __shared__ f16x8 UL[8192];     // 128 KB: ((cg*4+ks)*8+s8)*64 + l
  __shared__ float red[2048];    // 8 KB: slot(m*4+cg)*256 + l*4 + r (identity)

  const int tid = threadIdx.x;
  const int bx = blockIdx.x;
  const int l = tid & 63, w = tid >> 6;

  // --- stage U-hi into LDS once (coalesced: UL flat == Uhi flat per block) ---
#pragma unroll
  for (int i = 0; i < 16; ++i) {
    int flat = i * 512 + tid;
    UL[flat] = Uhi[(size_t)bx * 8192 + flat];
  }
  // zero red
  *(f32x4*)(&red[tid * 4]) = (f32x4){0.f, 0.f, 0.f, 0.f};

  // gate-thread constants: b = gb, unit gu (0..15); all 512 threads are gates
  const int gb = tid & 31, gu = tid >> 5;
  float bia[4];
#pragma unroll
  for (int g = 0; g < 4; ++g) bia[g] = bias[g * 1024 + bx * 16 + gu];
  const int widx = (((gb >> 4) * 128 + bx * 2 + (gu >> 3)) * 16 + (gb & 15)) * 4 +
                   ((gu & 7) >> 1);
  const int gslot = ((gb >> 4) * 4 + (gu >> 2)) * 256;   // red slot base
  float creg = 0.f;

  const int ks_w = w >> 1;
  const int xrow0 = (l & 15) * 512 + (l >> 4) * 8;
  const unsigned* myflg = flg + (w * 8 + (l & 7)) * 32;   // 8 producers/wave
  const size_t lobase = (size_t)(bx * 8 + w) * 16 * 64 + l;

  __syncthreads();   // U staged, red zeroed

  for (int t = 0; t < S_; ++t) {
    const ull* R64 = (const ull*)((t & 1) ? T0 : T1);   // h_{t-1}
    unsigned* WrT = (t & 1) ? T1 : T0;                  // h_t

    // --- U-lo frag reloads (L2-resident, no h dep) — issue before poll ---
    f16x8 ulo[4][4];
#pragma unroll
    for (int s = 0; s < 4; ++s)
#pragma unroll
      for (int cg = 0; cg < 4; ++cg)
        ulo[s][cg] = Ulo[lobase + (size_t)(s * 4 + cg) * 64];

    // --- xz prelude: acc = x_t @ W (fp16 MFMA), no h dependency ---
    f32x4 acc[4][2], accL[4][2];
#pragma unroll
    for (int cg = 0; cg < 4; ++cg)
#pragma unroll
      for (int m2 = 0; m2 < 2; ++m2) {
        acc[cg][m2] = (f32x4){0.f, 0.f, 0.f, 0.f};
        accL[cg][m2] = (f32x4){0.f, 0.f, 0.f, 0.f};
      }
    {
      const unsigned short* Xt = Xf16 + (size_t)t * 16384;
#pragma unroll
      for (int c2 = 0; c2 < 2; ++c2) {
        int kc = w * 2 + c2;
        f16x8 xa0 = *(const f16x8*)(Xt + xrow0 + kc * 32);
        f16x8 xa1 = *(const f16x8*)(Xt + 8192 + xrow0 + kc * 32);
#pragma unroll
        for (int cg = 0; cg < 4; ++cg) {
          f16x8 wb = *(const f16x8*)(Wf16 + ((size_t)((bx * 4 + cg) * 16 + kc) * 64 + l) * 8);
          acc[cg][0] = __builtin_amdgcn_mfma_f32_16x16x32_f16(xa0, wb, acc[cg][0], 0, 0, 0);
          acc[cg][1] = __builtin_amdgcn_mfma_f32_16x16x32_f16(xa1, wb, acc[cg][1], 0, 0, 0);
        }
      }
    }

    // --- recurrence ---
    if (t > 0) {
      while (true) {
        unsigned v = __hip_atomic_load(myflg, __ATOMIC_RELAXED, __HIP_MEMORY_SCOPE_AGENT);
        if (__all((int)(v >= (unsigned)t))) break;
        __builtin_amdgcn_s_sleep(1);
      }
      union F { ull q[2]; f16x8 v; };
      F A[2][4];
#pragma unroll
      for (int m2 = 0; m2 < 2; ++m2)
#pragma unroll
        for (int s = 0; s < 4; ++s) {
          int kidx = w * 16 + s * 4 + (l >> 4);
          int b64 = ((m2 * 128 + kidx) * 16 + (l & 15)) * 2;
          A[m2][s].q[0] = ldq(R64 + b64);
          A[m2][s].q[1] = ldq(R64 + b64 + 1);
        }
#pragma unroll
      for (int s = 0; s < 4; ++s) {
        int s8 = (w & 1) * 4 + s;
#pragma unroll
        for (int cg = 0; cg < 4; ++cg) {
          f16x8 uhf = UL[((cg * 4 + ks_w) * 8 + s8) * 64 + l];
          acc[cg][0]  = __builtin_amdgcn_mfma_f32_16x16x32_f16(A[0][s].v, uhf, acc[cg][0], 0, 0, 0);
          acc[cg][1]  = __builtin_amdgcn_mfma_f32_16x16x32_f16(A[1][s].v, uhf, acc[cg][1], 0, 0, 0);
          accL[cg][0] = __builtin_amdgcn_mfma_f32_16x16x32_f16(A[0][s].v, ulo[s][cg], accL[cg][0], 0, 0, 0);
          accL[cg][1] = __builtin_amdgcn_mfma_f32_16x16x32_f16(A[1][s].v, ulo[s][cg], accL[cg][1], 0, 0, 0);
        }
      }
    }

    // --- fold lo + LDS atomic reduce (rot staggers op order only; layout
    //     is IDENTITY: position l*4+j holds value v[j]) ---
    {
      const int rot = (l >> 3) & 3;
#pragma unroll
      for (int cg = 0; cg < 4; ++cg)
#pragma unroll
        for (int m2 = 0; m2 < 2; ++m2) {
          f32x4 v = acc[cg][m2] + accL[cg][m2] * 9.765625e-4f;
#pragma unroll
          for (int r = 0; r < 4; ++r)
            atomicAdd(&red[(m2 * 4 + cg) * 256 + l * 4 + ((r + rot) & 3)], v[(r + rot) & 3]);
        }
    }
    __syncthreads();

    // --- gates: read red (identity offsets), zero-in-place, compute, store h ---
    {
      float z[4];
#pragma unroll
      for (int g = 0; g < 4; ++g) {
        int le = ((gb & 15) >> 2) * 16 + (gu & 3) * 4 + g;
        int re = gb & 3;
        int phys = gslot + le * 4 + re;   // FIX: identity (was spuriously rotated)
        z[g] = red[phys] + bia[g];
        red[phys] = 0.f;
      }
      float ig = 1.f / (1.f + __expf(-z[0]));
      float fg = 1.f / (1.f + __expf(-z[1]));
      float gg = tanhf(z[2]);
      float og = 1.f / (1.f + __expf(-z[3]));
      creg = fg * creg + ig * gg;
      float hv = og * tanhf(creg);
      unsigned pk = (unsigned)__half_as_ushort(__float2half_rn(hv));
      unsigned other = (unsigned)__shfl_xor((int)pk, 32, 64);   // partner unit gu^1
      if ((gu & 1) == 0)
        stw(WrT + widx, (pk & 0xffffu) | (other << 16));
    }
    __syncthreads();   // zeros visible + h stores drained (vmcnt) before flag
    if (tid == 0)
      stw(flg + bx * 32, (unsigned)(t + 1));
  }
}

// ---------------------------------------------------------------------------
// K3: logits from pair-packed fp16 h (t=255 -> T1). grid 5, block 256.
__global__ __launch_bounds__(256) void k_head6(const unsigned* __restrict__ T,
                                               const float* __restrict__ Wd,
                                               const float* __restrict__ bd,
                                               float* __restrict__ out) {
  __shared__ float red[32 * 9];
  int lbl = blockIdx.x;
  int tid = threadIdx.x;
  int b = tid >> 3, ks = tid & 7;
  float acc = 0.f;
  for (int k = ks * 128; k < ks * 128 + 128; ++k) {
    int idx = (((b >> 4) * 128 + (k >> 3)) * 16 + (b & 15)) * 4 + ((k & 7) >> 1);
    unsigned wv = T[idx];
    unsigned short h16 = (unsigned short)((k & 1) ? (wv >> 16) : (wv & 0xffffu));
    acc += __half2float(__ushort_as_half(h16)) * Wd[k * NL_ + lbl];
  }
  red[b * 9 + ks] = acc;
  __syncthreads();
  if (tid < 32) {
    float s = bd[lbl];
#pragma unroll
    for (int i = 0; i < 8; ++i) s += red[tid * 9 + i];
    out[tid * NL_ + lbl] = s;
  }
}

// ---------------------------------------------------------------------------
extern "C" void kernel_launch(void* const* d_in, const int* in_sizes, int n_in,
                              void* d_out, int out_size, void* d_ws, size_t ws_size,
                              hipStream_t stream) {
  const int* tokens  = (const int*)d_in[0];
  const float* emb   = (const float*)d_in[1];
  const float* W     = (const float*)d_in[2];
  const float* U     = (const float*)d_in[3];
  const float* bias  = (const float*)d_in[4];
  const float* Wd    = (const float*)d_in[5];
  const float* bd    = (const float*)d_in[6];
  float* out = (float*)d_out;

  char* ws = (char*)d_ws;
  // Layout (≈58.9 MB, well under the proven 84.3 MB budget):
  //   Xf16 fp16 [256][32][512]  @ 0           (8 MiB)
  //   Wf16 fp16 frags           @ 8,388,608   (4 MiB)
  //   Ut fp32 (transient)       @ 16,777,216  (16 MiB)
  //   Wt fp32 (transient)       @ 33,554,432  (8 MiB)
  //   Uhi fp16 frags            @ 41,943,040  (8 MiB)
  //   Ulo fp16 frags            @ 50,331,648  (8 MiB)
  //   T0, T1 (64 KB each)       @ 58,720,256
  //   flg (64 x 128 B)          @ 58,851,328  (8 KB, zeroed each launch)
  unsigned short* Xf16 = (unsigned short*)ws;
  unsigned short* Wf16 = (unsigned short*)(ws + 8388608);
  float* Ut          = (float*)(ws + 16777216);
  float* Wt          = (float*)(ws + 33554432);
  f16x8* Uhi         = (f16x8*)(ws + 41943040);
  f16x8* Ulo         = (f16x8*)(ws + 50331648);
  unsigned* T0       = (unsigned*)(ws + 58720256);
  unsigned* T1       = (unsigned*)(ws + 58785792);
  unsigned* flg      = (unsigned*)(ws + 58851328);

  hipMemsetAsync(flg, 0, 8192, stream);
  k_transposeK<<<dim3(128, 32), 256, 0, stream>>>(U, Ut, 1024);
  k_prepU162<<<2048, 256, 0, stream>>>(Ut, Uhi, Ulo);
  k_transposeK<<<dim3(128, 16), 256, 0, stream>>>(W, Wt, 512);
  k_prepW16<<<1024, 256, 0, stream>>>(Wt, Wf16);
  k_prepX<<<2048, 256, 0, stream>>>(tokens, emb, Xf16);

  k_steps8<<<NBLK, 512, 0, stream>>>(Uhi, Ulo, Wf16, Xf16, bias, T0, T1, flg);

  // t=255 (odd) wrote T1
  k_head6<<<NL_, 256, 0, stream>>>(T1, Wd, bd, out);
}

// Round 13
// 966.176 us; speedup vs baseline: 6.3097x; 6.3097x over previous
//
#include <hip/hip_runtime.h>
#include <hip/hip_fp16.h>

#define B_   32
#define S_   256
#define EMB_ 512
#define H_   1024
#define G4_  4096
#define NL_  5
#define NBLK 128

typedef _Float16 f16x8 __attribute__((ext_vector_type(8)));
typedef float f32x4 __attribute__((ext_vector_type(4)));
typedef unsigned long long ull;

__device__ inline ull ldq(const ull* p) {
  return __hip_atomic_load(p, __ATOMIC_RELAXED, __HIP_MEMORY_SCOPE_AGENT);
}
__device__ inline void stw(unsigned* p, unsigned v) {
  __hip_atomic_store(p, v, __ATOMIC_RELAXED, __HIP_MEMORY_SCOPE_AGENT);
}

// ---------------------------------------------------------------------------
// K0: transpose src [K][4096] -> dst [4096][K]. grid (128, K/32).
__global__ __launch_bounds__(256) void k_transposeK(const float* __restrict__ src,
                                                    float* __restrict__ dst, int K) {
  __shared__ float tile[32][33];
  int c0 = blockIdx.x * 32, k0 = blockIdx.y * 32;
  int tx = threadIdx.x & 31, ty = threadIdx.x >> 5;
#pragma unroll
  for (int i = 0; i < 4; ++i)
    tile[ty + 8 * i][tx] = src[(size_t)(k0 + ty + 8 * i) * G4_ + c0 + tx];
  __syncthreads();
#pragma unroll
  for (int i = 0; i < 4; ++i)
    dst[(size_t)(c0 + ty + 8 * i) * K + k0 + tx] = tile[tx][ty + 8 * i];
}

// ---------------------------------------------------------------------------
// K0b: U -> fp16 MFMA B-fragments, hi plane + lo*1024 plane (r10-proven).
// Ubf[((ug*4 + ks)*8 + s8)*128 + plane*64 + l]: value U[k][gcol],
// k = ks*256 + s8*32 + (l>>4)*8 + j, n16=l&15, gcol=(n16&3)*1024+ug*4+(n16>>2).
__global__ __launch_bounds__(256) void k_prepU16(const float* __restrict__ Ut,
                                                 f16x8* __restrict__ Ubf) {
  int gid = blockIdx.x * 256 + threadIdx.x;
  int l = gid & 63;
  int bxws = gid >> 6;
  int n = l & 15, kgrp = l >> 4;
  int s = bxws & 7, bw = bxws >> 3;
  int w = bw & 3, bx = bw >> 2;
  int g = n & 3, ju = n >> 2;
  int gcol = g * 1024 + bx * 4 + ju;
  int kbase = w * 256 + s * 32 + kgrp * 8;
  const float4* f = (const float4*)(Ut + (size_t)gcol * H_ + kbase);
  float4 f0 = f[0], f1 = f[1];
  float v[8] = {f0.x, f0.y, f0.z, f0.w, f1.x, f1.y, f1.z, f1.w};
  f16x8 vh, vl;
#pragma unroll
  for (int j = 0; j < 8; ++j) {
    _Float16 hi = (_Float16)v[j];
    vh[j] = hi;
    vl[j] = (_Float16)((v[j] - (float)hi) * 1024.f);
  }
  Ubf[(size_t)bxws * 128 + l] = vh;
  Ubf[(size_t)bxws * 128 + 64 + l] = vl;
}

// ---------------------------------------------------------------------------
// K0c: W -> fp16 MFMA B-fragments (single plane). (proven)
__global__ __launch_bounds__(256) void k_prepW16(const float* __restrict__ Wt,
                                                 unsigned short* __restrict__ Wf16) {
  int gid = blockIdx.x * 256 + threadIdx.x;   // 262144 total
  int l = gid & 63, fi = gid >> 6;
  int kc = fi & 15, ug = fi >> 4;
  int n16 = l & 15, kgrp = l >> 4;
  int gcol = (n16 & 3) * 1024 + ug * 4 + (n16 >> 2);
  const float4* f = (const float4*)(Wt + (size_t)gcol * 512 + kc * 32 + kgrp * 8);
  float4 f0 = f[0], f1 = f[1];
  float v[8] = {f0.x, f0.y, f0.z, f0.w, f1.x, f1.y, f1.z, f1.w};
  union { unsigned short u[8]; uint4 q; } o;
#pragma unroll
  for (int j = 0; j < 8; ++j) o.u[j] = __half_as_ushort(__float2half_rn(v[j]));
  *(uint4*)(Wf16 + ((size_t)fi * 64 + l) * 8) = o.q;
}

// ---------------------------------------------------------------------------
// K0d: gather emb rows -> Xf16 [256 s][32 b][512 e] fp16. (proven)
__global__ __launch_bounds__(256) void k_prepX(const int* __restrict__ tokens,
                                               const float* __restrict__ emb,
                                               unsigned short* __restrict__ Xf16) {
  int gid = blockIdx.x * 256 + threadIdx.x;   // 524288 total
  int seg = gid & 63, row = gid >> 6;
  int s = row >> 5, b = row & 31;
  int tok = tokens[b * 256 + s];
  const float4* f = (const float4*)(emb + (size_t)tok * EMB_ + seg * 8);
  float4 f0 = f[0], f1 = f[1];
  float v[8] = {f0.x, f0.y, f0.z, f0.w, f1.x, f1.y, f1.z, f1.w};
  union { unsigned short u[8]; uint4 q; } o;
#pragma unroll
  for (int j = 0; j < 8; ++j) o.u[j] = __half_as_ushort(__float2half_rn(v[j]));
  *(uint4*)(Xf16 + (size_t)row * 512 + seg * 8) = o.q;
}

// ---------------------------------------------------------------------------
// K2: persistent steps v9 = r9's proven skeleton (128 x 512, two-pass LDS
// reduction, per-producer flags) + fp16 pair-packed h (r12-verified) + fp16
// U hi/lo*1024 planes in LDS (r10-verified). Block bx owns 8 units (32 gate
// cols, cg 0..1); wave w = K-slice [w*128,(w+1)*128).
// h word idx: ((m*128 + kidx)*16 + row)*4 + (j>>1); b=m*16+row, k=kidx*8+j.
__global__ __launch_bounds__(512, 2) void k_steps9(
    const f16x8* __restrict__ Ubf,
    const unsigned short* __restrict__ Wf16,
    const unsigned short* __restrict__ Xf16,
    const float* __restrict__ bias,
    unsigned* __restrict__ T0, unsigned* __restrict__ T1,
    unsigned* __restrict__ flg) {
  __shared__ f16x8 UL[8192];      // 128 KB: cg*4096 + pl*2048 + ks*512 + s8*64 + l
  __shared__ float red[4096];     // 16 KB
  __shared__ float zg[1056];      // [b][c] stride 33
  __shared__ float bias_s[32];

  const int tid = threadIdx.x;
  const int bx = blockIdx.x;
  const int l = tid & 63, w = tid >> 6;

  // --- stage U (hi+lo planes) into LDS once ---
#pragma unroll
  for (int i = 0; i < 16; ++i) {
    int flat = i * 512 + tid;
    int ll = flat & 63, s8 = (flat >> 6) & 7, ks = (flat >> 9) & 3;
    int pl = (flat >> 11) & 1, cg = flat >> 12;
    size_t fi = (size_t)((bx * 2 + cg) * 4 + ks) * 8 + s8;
    UL[flat] = Ubf[fi * 128 + pl * 64 + ll];
  }
  if (tid < 32) {
    int cg = tid >> 4, n16 = tid & 15;
    bias_s[tid] = bias[(n16 & 3) * 1024 + (bx * 2 + cg) * 4 + (n16 >> 2)];
  }

  // reducer mapping (r9)
  const int e = tid & 255, m = tid >> 8;
  const int n16r = (e >> 2) & 15;
  const int zb = m * 16 + (e >> 6) * 4 + (e & 3);

  // gate mapping (tid<256): b=gb, unit gu (0..7); pair-packed h word index
  const int gb = tid & 31, gu = tid >> 5;
  const int widx = (((gb >> 4) * 128 + bx) * 16 + (gb & 15)) * 4 + (gu >> 1);
  const int zrd = gb * 33 + (gu >> 2) * 16 + (gu & 3) * 4;
  float creg = 0.f;

  const int ks_w = w >> 1;
  const int xrow0 = (l & 15) * 512 + (l >> 4) * 8;
  const unsigned* myflg = flg + (w * 16 + (l & 15)) * 32;   // 16 producers/wave

  __syncthreads();   // U staged

  for (int t = 0; t < S_; ++t) {
    const ull* R64 = (const ull*)((t & 1) ? T0 : T1);   // h_{t-1}
    unsigned* WrT = (t & 1) ? T1 : T0;                  // h_t

    // ---- xz prelude: acc = x_t @ W (fp16 MFMA), no h dependency ----
    f32x4 acc[2][2], accL[2][2];
#pragma unroll
    for (int cg = 0; cg < 2; ++cg)
#pragma unroll
      for (int m2 = 0; m2 < 2; ++m2) {
        acc[cg][m2] = (f32x4){0.f, 0.f, 0.f, 0.f};
        accL[cg][m2] = (f32x4){0.f, 0.f, 0.f, 0.f};
      }
    {
      const unsigned short* Xt = Xf16 + (size_t)t * 16384;
#pragma unroll
      for (int c2 = 0; c2 < 2; ++c2) {
        int kc = w * 2 + c2;
        f16x8 xa0 = *(const f16x8*)(Xt + xrow0 + kc * 32);
        f16x8 xa1 = *(const f16x8*)(Xt + 8192 + xrow0 + kc * 32);
        f16x8 wb0 = *(const f16x8*)(Wf16 + ((size_t)((bx * 2 + 0) * 16 + kc) * 64 + l) * 8);
        f16x8 wb1 = *(const f16x8*)(Wf16 + ((size_t)((bx * 2 + 1) * 16 + kc) * 64 + l) * 8);
        acc[0][0] = __builtin_amdgcn_mfma_f32_16x16x32_f16(xa0, wb0, acc[0][0], 0, 0, 0);
        acc[0][1] = __builtin_amdgcn_mfma_f32_16x16x32_f16(xa1, wb0, acc[0][1], 0, 0, 0);
        acc[1][0] = __builtin_amdgcn_mfma_f32_16x16x32_f16(xa0, wb1, acc[1][0], 0, 0, 0);
        acc[1][1] = __builtin_amdgcn_mfma_f32_16x16x32_f16(xa1, wb1, acc[1][1], 0, 0, 0);
      }
    }

    // ---- recurrence: poll flags, pair-packed fp16 A loads, MFMA ----
    if (t > 0) {
      while (true) {
        unsigned v = __hip_atomic_load(myflg, __ATOMIC_RELAXED, __HIP_MEMORY_SCOPE_AGENT);
        if (__all((int)(v >= (unsigned)t))) break;
        __builtin_amdgcn_s_sleep(1);
      }
      union F { ull q[2]; f16x8 v; };
      F A[2][4];
#pragma unroll
      for (int m2 = 0; m2 < 2; ++m2)
#pragma unroll
        for (int s = 0; s < 4; ++s) {
          int kidx = w * 16 + s * 4 + (l >> 4);
          int b64 = ((m2 * 128 + kidx) * 16 + (l & 15)) * 2;
          A[m2][s].q[0] = ldq(R64 + b64);
          A[m2][s].q[1] = ldq(R64 + b64 + 1);
        }
#pragma unroll
      for (int s = 0; s < 4; ++s) {
        int s8 = (w & 1) * 4 + s;
#pragma unroll
        for (int cg = 0; cg < 2; ++cg) {
          f16x8 uhf = UL[cg * 4096 + ks_w * 512 + s8 * 64 + l];
          f16x8 ulf = UL[cg * 4096 + 2048 + ks_w * 512 + s8 * 64 + l];
          acc[cg][0]  = __builtin_amdgcn_mfma_f32_16x16x32_f16(A[0][s].v, uhf, acc[cg][0], 0, 0, 0);
          acc[cg][1]  = __builtin_amdgcn_mfma_f32_16x16x32_f16(A[1][s].v, uhf, acc[cg][1], 0, 0, 0);
          accL[cg][0] = __builtin_amdgcn_mfma_f32_16x16x32_f16(A[0][s].v, ulf, accL[cg][0], 0, 0, 0);
          accL[cg][1] = __builtin_amdgcn_mfma_f32_16x16x32_f16(A[1][s].v, ulf, accL[cg][1], 0, 0, 0);
        }
      }
    }

    // fold lo-plane: z = acc + accL/1024
#pragma unroll
    for (int cg = 0; cg < 2; ++cg)
#pragma unroll
      for (int m2 = 0; m2 < 2; ++m2)
        acc[cg][m2] += accL[cg][m2] * 9.765625e-4f;

    // ---- two-pass reduction (r9-proven) ----
    if (w < 4) {
#pragma unroll
      for (int cg = 0; cg < 2; ++cg) {
        *(f32x4*)(&red[((w * 2 + 0) * 2 + cg) * 256 + l * 4]) = acc[cg][0];
        *(f32x4*)(&red[((w * 2 + 1) * 2 + cg) * 256 + l * 4]) = acc[cg][1];
      }
    }
    __syncthreads();
    if (w >= 4) {
      int w4 = w - 4;
#pragma unroll
      for (int cg = 0; cg < 2; ++cg) {
        f32x4* p0 = (f32x4*)(&red[((w4 * 2 + 0) * 2 + cg) * 256 + l * 4]);
        f32x4* p1 = (f32x4*)(&red[((w4 * 2 + 1) * 2 + cg) * 256 + l * 4]);
        *p0 += acc[cg][0];
        *p1 += acc[cg][1];
      }
    }
    __syncthreads();

    // ---- final reduce + fp32 bias -> zg ----
    {
      float z0 = bias_s[n16r], z1 = bias_s[16 + n16r];
#pragma unroll
      for (int w4 = 0; w4 < 4; ++w4) {
        z0 += red[((w4 * 2 + m) * 2 + 0) * 256 + e];
        z1 += red[((w4 * 2 + m) * 2 + 1) * 256 + e];
      }
      zg[zb * 33 + n16r] = z0;
      zg[zb * 33 + 16 + n16r] = z1;
    }
    __syncthreads();

    // ---- gates + pair-packed fp16 h store ----
    if (tid < 256) {
      float zi = zg[zrd + 0];
      float zf = zg[zrd + 1];
      float zc_ = zg[zrd + 2];
      float zo = zg[zrd + 3];
      float ig = 1.f / (1.f + __expf(-zi));
      float fg = 1.f / (1.f + __expf(-zf));
      float gg = tanhf(zc_);
      float og = 1.f / (1.f + __expf(-zo));
      creg = fg * creg + ig * gg;
      float hv = og * tanhf(creg);
      unsigned pk = (unsigned)__half_as_ushort(__float2half_rn(hv));
      unsigned other = (unsigned)__shfl_xor((int)pk, 32, 64);   // partner unit gu^1
      if ((gu & 1) == 0)
        stw(WrT + widx, (pk & 0xffffu) | (other << 16));
    }
    __syncthreads();   // h stores drained (vmcnt) before flag
    if (tid == 0)
      stw(flg + bx * 32, (unsigned)(t + 1));
  }
}

// ---------------------------------------------------------------------------
// K3: logits from pair-packed fp16 h (t=255 -> T1). grid 5, block 256.
__global__ __launch_bounds__(256) void k_head6(const unsigned* __restrict__ T,
                                               const float* __restrict__ Wd,
                                               const float* __restrict__ bd,
                                               float* __restrict__ out) {
  __shared__ float red[32 * 9];
  int lbl = blockIdx.x;
  int tid = threadIdx.x;
  int b = tid >> 3, ks = tid & 7;
  float acc = 0.f;
  for (int k = ks * 128; k < ks * 128 + 128; ++k) {
    int idx = (((b >> 4) * 128 + (k >> 3)) * 16 + (b & 15)) * 4 + ((k & 7) >> 1);
    unsigned wv = T[idx];
    unsigned short h16 = (unsigned short)((k & 1) ? (wv >> 16) : (wv & 0xffffu));
    acc += __half2float(__ushort_as_half(h16)) * Wd[k * NL_ + lbl];
  }
  red[b * 9 + ks] = acc;
  __syncthreads();
  if (tid < 32) {
    float s = bd[lbl];
#pragma unroll
    for (int i = 0; i < 8; ++i) s += red[tid * 9 + i];
    out[tid * NL_ + lbl] = s;
  }
}

// ---------------------------------------------------------------------------
extern "C" void kernel_launch(void* const* d_in, const int* in_sizes, int n_in,
                              void* d_out, int out_size, void* d_ws, size_t ws_size,
                              hipStream_t stream) {
  const int* tokens  = (const int*)d_in[0];
  const float* emb   = (const float*)d_in[1];
  const float* W     = (const float*)d_in[2];
  const float* U     = (const float*)d_in[3];
  const float* bias  = (const float*)d_in[4];
  const float* Wd    = (const float*)d_in[5];
  const float* bd    = (const float*)d_in[6];
  float* out = (float*)d_out;

  char* ws = (char*)d_ws;
  // Layout (≈50.5 MB):
  //   Xf16 fp16 [256][32][512]  @ 0           (8 MiB)
  //   Wf16 fp16 frags           @ 8,388,608   (4 MiB)
  //   Ut fp32 (transient)       @ 16,777,216  (16 MiB)
  //   Wt fp32 (transient)       @ 33,554,432  (8 MiB)
  //   Ubf fp16 hi/lo frags      @ 41,943,040  (8 MiB)
  //   T0, T1 (64 KB each)       @ 50,331,648
  //   flg (128 x 128 B)         @ 50,462,720  (16 KB, zeroed each launch)
  unsigned short* Xf16 = (unsigned short*)ws;
  unsigned short* Wf16 = (unsigned short*)(ws + 8388608);
  float* Ut          = (float*)(ws + 16777216);
  float* Wt          = (float*)(ws + 33554432);
  f16x8* Ubf         = (f16x8*)(ws + 41943040);
  unsigned* T0       = (unsigned*)(ws + 50331648);
  unsigned* T1       = (unsigned*)(ws + 50397184);
  unsigned* flg      = (unsigned*)(ws + 50462720);

  hipMemsetAsync(flg, 0, 16384, stream);
  k_transposeK<<<dim3(128, 32), 256, 0, stream>>>(U, Ut, 1024);
  k_prepU16<<<2048, 256, 0, stream>>>(Ut, Ubf);
  k_transposeK<<<dim3(128, 16), 256, 0, stream>>>(W, Wt, 512);
  k_prepW16<<<1024, 256, 0, stream>>>(Wt, Wf16);
  k_prepX<<<2048, 256, 0, stream>>>(tokens, emb, Xf16);

  k_steps9<<<NBLK, 512, 0, stream>>>(Ubf, Wf16, Xf16, bias, T0, T1, flg);

  // t=255 (odd) wrote T1
  k_head6<<<NL_, 256, 0, stream>>>(T1, Wd, bd, out);
}